// Round 3
// baseline (450.297 us; speedup 1.0000x reference)
//
#include <hip/hip_runtime.h>

// Additive (Bahdanau) attention, fused pass over encoder_outputs.
// enc: (32, 8192, 256) fp32 is the only big tensor (256 MiB) -> HBM floor ~43us.
//
// R8: split into BW-saturating streaming kernels. R7 (wave-autonomous, barrier-
// free) still landed ~130-140us for attn_main: per-CU global stream is 2MB
// (frags + ctx re-read) but each wave only has loads in flight ~5% of its life
// -> ~2TB/s achieved. The context phase (latency-exposed loads + readlane FMA
// chain after softmax) was the main serializer.
//  - attn_scores: R7 main minus context; stores softmax weights e (1MB). Per CU
//    streams 1MB enc with 16 waves demanding ~11x fair-share BW -> HBM-bound.
//  - ctx_kernel: 8192 blocks x 256 thr, one 32-row chunk each: pure streaming
//    weighted column-sum, fully coalesced, 32 outstanding loads/thread, weights
//    via uniform s_loads. enc re-read is L2/L3-assisted.
//  - prep/finish unchanged (verified).
//
// History:
//  R2: 209us  R4: 191us  R5: B-in-regs: 413 total  R6: 4-chunk pipeline:
//  458 total (main 178, occ 22%, MfmaUtil 7.6%)  R7: barrier-free 16-wave:
//  419 total (main ~135 inferred, hidden under 159us fill cutoff)

typedef _Float16 f16x8 __attribute__((ext_vector_type(8)));
typedef float    f32x4 __attribute__((ext_vector_type(4)));

__device__ __forceinline__ float fast_tanh(float x){
  x = fminf(15.f, fmaxf(-15.f, x));
  float e = __expf(2.f * x);
  return (e - 1.f) * __builtin_amdgcn_rcpf(e + 1.f);
}

// ---------------- prep (unchanged) ----------------
__global__ void prep_kernel(const float* __restrict__ hidden, const float* __restrict__ W,
                            const float* __restrict__ bias, _Float16* __restrict__ Bfrag,
                            float* __restrict__ qb)
{
  int blk = blockIdx.x;
  if (blk < 256){
    int tid  = blk * 256 + threadIdx.x;      // 0..65535
    int j    = tid & 7;
    int lane = (tid >> 3) & 63;
    int kc   = (tid >> 9) & 7;
    int nt   = tid >> 12;
    int lc   = lane & 15, q = lane >> 4;
    int row  = nt * 16 + lc;                 // output-k index
    int col  = 256 + kc * 32 + q * 8 + j;    // W column (h + 256)
    Bfrag[tid] = (_Float16)W[row * 512 + col];
  } else {
    int b = blk - 256;
    int k = threadIdx.x;
    const float4* hp = (const float4*)(hidden + b * 256);
    const float4* wp = (const float4*)(W + k * 512);
    float s = 0.f;
    for (int i = 0; i < 64; i++){
      float4 h4 = hp[i], w4 = wp[i];
      s += h4.x * w4.x + h4.y * w4.y + h4.z * w4.z + h4.w * w4.w;
    }
    qb[b * 256 + k] = s + bias[k];
  }
}

// ---------------- scores ----------------
// grid = 256 (32 b x 8 slabs), block = 1024 (16 waves). wave w owns rows
// [w*64, w*64+64) of its slab = 2 chunks of 32 rows, independent after the one
// staging barrier. Output: logits, unnormalized weights swg, per-chunk m/l.
__global__ __launch_bounds__(1024) void attn_scores(
    const float* __restrict__ enc, const _Float16* __restrict__ Bfrag,
    const float* __restrict__ qb, const float* __restrict__ v,
    float* __restrict__ logits, float* __restrict__ swg,
    float* __restrict__ mw, float* __restrict__ lw)
{
  __shared__ _Float16 Wf[65536];   // 128 KiB: We fragments (A-operand), frag order
  __shared__ float2 qv2[256];      // {qb[b][k], v[k]}

  const int tid = threadIdx.x, wv = tid >> 6, lane = tid & 63;
  const int q = lane >> 4, lc = lane & 15;
  const int b = blockIdx.x >> 3, slab = blockIdx.x & 7;

  // ---- stage We-frags (128 KiB) + qv2, ONCE per block ----
  {
    const float4* src = (const float4*)Bfrag;
    float4* dst = (float4*)Wf;
    #pragma unroll
    for (int i = 0; i < 8; i++) dst[tid + i * 1024] = src[tid + i * 1024];
    if (tid < 256) qv2[tid] = make_float2(qb[b * 256 + tid], v[tid]);
  }
  __syncthreads();           // the ONLY barrier

  const f16x8* Wl = (const f16x8*)Wf;
  const int rowBase0 = b * 8192 + (slab * 32 + wv * 2) * 32;

  // enc B-fragment loader: lane holds row (base+lc [+16 for tile 1]),
  // cols q*8..q*8+7 (+kc*32).
  f16x8 bf[2][8];
  #define LOAD_BF(base)                                                     \
  {                                                                         \
    const float* er0 = enc + (size_t)((base) + lc) * 256 + q * 8;           \
    _Pragma("unroll")                                                       \
    for (int t = 0; t < 2; t++){                                            \
      const float* er = er0 + t * 16 * 256;                                 \
      _Pragma("unroll")                                                     \
      for (int kc = 0; kc < 8; kc++){                                       \
        float4 x0 = *(const float4*)(er + kc * 32);                         \
        float4 x1 = *(const float4*)(er + kc * 32 + 4);                     \
        f16x8 h;                                                            \
        h[0]=(_Float16)x0.x; h[1]=(_Float16)x0.y;                           \
        h[2]=(_Float16)x0.z; h[3]=(_Float16)x0.w;                           \
        h[4]=(_Float16)x1.x; h[5]=(_Float16)x1.y;                           \
        h[6]=(_Float16)x1.z; h[7]=(_Float16)x1.w;                           \
        bf[t][kc] = h;                                                      \
      }                                                                     \
    }                                                                       \
  }

  LOAD_BF(rowBase0)

  for (int ci = 0; ci < 2; ci++){
    const int rowBase = rowBase0 + ci * 32;
    const int cid = b * 256 + slab * 32 + wv * 2 + ci;

    // ---- scores^T GEMM: D[kout = q*4+rr (+16nt)][row = lc (+16t)] ----
    float lg0 = 0.f, lg1 = 0.f;
    #pragma unroll 2
    for (int nt = 0; nt < 16; nt++){
      f32x4 acc0 = {0, 0, 0, 0}, acc1 = {0, 0, 0, 0};
      #pragma unroll
      for (int kc = 0; kc < 8; kc++){
        f16x8 a = Wl[(nt * 8 + kc) * 64 + lane];
        acc0 = __builtin_amdgcn_mfma_f32_16x16x32_f16(a, bf[0][kc], acc0, 0, 0, 0);
        acc1 = __builtin_amdgcn_mfma_f32_16x16x32_f16(a, bf[1][kc], acc1, 0, 0, 0);
      }
      #pragma unroll
      for (int rr = 0; rr < 4; rr++){
        float2 c = qv2[nt * 16 + q * 4 + rr];
        lg0 += fast_tanh(acc0[rr] + c.x) * c.y;
        lg1 += fast_tanh(acc1[rr] + c.x) * c.y;
      }
    }

    // ---- prefetch next chunk's fragments (bf free now); hides under epilogue --
    if (ci == 0) LOAD_BF(rowBase0 + 32)

    // finish logits: sum the 4 kout-groups (q); result replicated over q
    lg0 += __shfl_xor(lg0, 16); lg0 += __shfl_xor(lg0, 32);
    lg1 += __shfl_xor(lg1, 16); lg1 += __shfl_xor(lg1, 32);
    if (q == 0){
      logits[rowBase + lc]      = lg0;
      logits[rowBase + 16 + lc] = lg1;
    }
    // ---- wave-local softmax over 32 rows ----
    float m = fmaxf(lg0, lg1);
    m = fmaxf(m, __shfl_xor(m, 1)); m = fmaxf(m, __shfl_xor(m, 2));
    m = fmaxf(m, __shfl_xor(m, 4)); m = fmaxf(m, __shfl_xor(m, 8));
    float e0 = __expf(lg0 - m), e1 = __expf(lg1 - m);
    float ls = e0 + e1;
    ls += __shfl_xor(ls, 1); ls += __shfl_xor(ls, 2);
    ls += __shfl_xor(ls, 4); ls += __shfl_xor(ls, 8);
    if (lane == 0){ mw[cid] = m; lw[cid] = ls; }
    if (q == 0){
      swg[cid * 32 + lc]      = e0;
      swg[cid * 32 + 16 + lc] = e1;
    }
  }
  #undef LOAD_BF
}

// ---------------- context ----------------
// grid = 8192 (one 32-row chunk each; rows are contiguous: rowBase = cid*32),
// block = 256 (thread t = output column k). Pure streaming weighted column-sum.
__global__ __launch_bounds__(256) void ctx_kernel(
    const float* __restrict__ enc, const float* __restrict__ swg,
    float* __restrict__ P)
{
  const int cid = blockIdx.x, t = threadIdx.x;
  const float* ep = enc + (size_t)cid * 32 * 256 + t;
  const float* wp = swg + cid * 32;          // uniform -> s_loads
  float acc = 0.f;
  #pragma unroll
  for (int r = 0; r < 32; r++) acc += wp[r] * ep[(size_t)r * 256];
  P[(size_t)cid * 256 + t] = acc;
}

// ---------------- finish ----------------
// grid = 64 (2 per batch: half 0 also does context; weights split), block = 256
__global__ void attn_finish(const float* __restrict__ logits, const float* __restrict__ P,
                            const float* __restrict__ mw, const float* __restrict__ lw,
                            float* __restrict__ out)
{
  const int b = blockIdx.x >> 1, half = blockIdx.x & 1, t = threadIdx.x;
  __shared__ float se[256], red[8];
  float mv = mw[b * 256 + t], lv = lw[b * 256 + t];
  float m = mv;
  #pragma unroll
  for (int o = 1; o < 64; o <<= 1) m = fmaxf(m, __shfl_xor(m, o));
  if ((t & 63) == 0) red[t >> 6] = m;
  __syncthreads();
  const float M = fmaxf(fmaxf(red[0], red[1]), fmaxf(red[2], red[3]));
  float e = __expf(mv - M);
  se[t] = e;
  float l = e * lv;
  #pragma unroll
  for (int o = 1; o < 64; o <<= 1) l += __shfl_xor(l, o);
  if ((t & 63) == 0) red[4 + (t >> 6)] = l;
  __syncthreads();
  const float L = red[4] + red[5] + red[6] + red[7];
  const float inv = 1.f / L;
  if (half == 0){
    float c0 = 0.f, c1 = 0.f;
    #pragma unroll 8
    for (int ch = 0; ch < 128; ch++){
      c0 += se[ch]       * P[(size_t)(b * 256 + ch) * 256 + t];
      c1 += se[ch + 128] * P[(size_t)(b * 256 + 128 + ch) * 256 + t];
    }
    out[b * 256 + t] = (c0 + c1) * inv;
  }
  const float* lg = logits + (size_t)b * 8192 + half * 4096;
  float* ao = out + 8192 + (size_t)b * 8192 + half * 4096;
  #pragma unroll
  for (int s2 = 0; s2 < 16; s2++) ao[s2 * 256 + t] = __expf(lg[s2 * 256 + t] - M) * inv;
}

extern "C" void kernel_launch(void* const* d_in, const int* in_sizes, int n_in,
                              void* d_out, int out_size, void* d_ws, size_t ws_size,
                              hipStream_t stream)
{
  const float* hidden = (const float*)d_in[0];   // (1,32,256)
  const float* enc    = (const float*)d_in[1];   // (32,8192,256)
  const float* W      = (const float*)d_in[2];   // (256,512)
  const float* bias   = (const float*)d_in[3];   // (256,)
  const float* v      = (const float*)d_in[4];   // (256,)
  float* out = (float*)d_out;

  char* ws = (char*)d_ws;
  _Float16* Bfrag = (_Float16*)ws;                                       // 128 KiB
  float* qb     = (float*)(ws + (128 << 10));                            // 32 KiB
  float* logits = (float*)(ws + (160 << 10));                            // 1 MiB
  float* P      = (float*)(ws + (160 << 10) + (1 << 20));                // 8 MiB (8192*256*4)
  float* mw     = (float*)(ws + (160 << 10) + (9 << 20));                // 32 KiB
  float* lw     = (float*)(ws + (160 << 10) + (9 << 20) + (32 << 10));   // 32 KiB
  float* swg    = (float*)(ws + (160 << 10) + (9 << 20) + (64 << 10));   // 1 MiB (8192*32*4)

  prep_kernel<<<288, 256, 0, stream>>>(hidden, W, bias, Bfrag, qb);
  attn_scores<<<256, 1024, 0, stream>>>(enc, Bfrag, qb, v, logits, swg, mw, lw);
  ctx_kernel<<<8192, 256, 0, stream>>>(enc, swg, P);
  attn_finish<<<64, 256, 0, stream>>>(logits, P, mw, lw, out);
}

// Round 4
// 429.925 us; speedup vs baseline: 1.0474x; 1.0474x over previous
//
#include <hip/hip_runtime.h>

// Additive (Bahdanau) attention, fused single-pass over encoder_outputs.
// enc: (32, 8192, 256) fp32 is the only big tensor (256 MiB) -> HBM floor ~43us.
//
// R9: register-pipelined fused main. Evidence so far:
//  - R6 (barriered, measured): 178us, MfmaUtil 7.6%, VALUBusy 18%, occ 22% ->
//    latency-bound; FETCH 242MB < 2x268 -> fused ctx re-read is L3-absorbed.
//  - R7 (fused, barrier-free, 1024thr): ~130us inferred. 16 waves/block forces
//    VGPR<=128 -> no room to keep next chunk's loads in flight during MFMA;
//    waves phase-locked after the single barrier (convoy) -> ~5% load duty.
//  - R8 (split ctx kernel): +31us vs R7 -> ctx re-read must stay fused/L3-hot.
// R9 structure: 512-thr blocks (8 waves), grid 512, 2 chunks of 32 rows/wave.
// 2 waves/SIMD -> VGPR cap 256. Pipeline per wave:
//   LOAD_RAW(c0) -> stage We -> CVT0 -> barrier -> LOAD_RAW(c1)[128 regs,
//   outstanding] -> MFMA0 (c1 loads land underneath) -> CVT1 -> sm0+ctx0 ->
//   MFMA1 -> sm1+ctx1.  Peak ~230 VGPR, no barrier after init, setprio on MFMA.
//
// History: R2 209 / R4 191 / R5 413 total / R6 458 / R7 419 / R8 450 (totals
// include ~265us of harness fill+fixed overhead; fills are 160us @1GiB).

typedef _Float16 f16x8 __attribute__((ext_vector_type(8)));
typedef float    f32x4 __attribute__((ext_vector_type(4)));

__device__ __forceinline__ float fast_tanh(float x){
  x = fminf(15.f, fmaxf(-15.f, x));
  float e = __expf(2.f * x);
  return (e - 1.f) * __builtin_amdgcn_rcpf(e + 1.f);
}

__device__ __forceinline__ float lane_bcast(float x, int l){
  return __uint_as_float(__builtin_amdgcn_readlane(__float_as_uint(x), l));
}

// ---------------- prep (unchanged, verified) ----------------
__global__ void prep_kernel(const float* __restrict__ hidden, const float* __restrict__ W,
                            const float* __restrict__ bias, _Float16* __restrict__ Bfrag,
                            float* __restrict__ qb)
{
  int blk = blockIdx.x;
  if (blk < 256){
    int tid  = blk * 256 + threadIdx.x;      // 0..65535
    int j    = tid & 7;
    int lane = (tid >> 3) & 63;
    int kc   = (tid >> 9) & 7;
    int nt   = tid >> 12;
    int lc   = lane & 15, q = lane >> 4;
    int row  = nt * 16 + lc;                 // output-k index
    int col  = 256 + kc * 32 + q * 8 + j;    // W column (h + 256)
    Bfrag[tid] = (_Float16)W[row * 512 + col];
  } else {
    int b = blk - 256;
    int k = threadIdx.x;
    const float4* hp = (const float4*)(hidden + b * 256);
    const float4* wp = (const float4*)(W + k * 512);
    float s = 0.f;
    for (int i = 0; i < 64; i++){
      float4 h4 = hp[i], w4 = wp[i];
      s += h4.x * w4.x + h4.y * w4.y + h4.z * w4.z + h4.w * w4.w;
    }
    qb[b * 256 + k] = s + bias[k];
  }
}

// ---------------- main ----------------
// grid = 512 (32 b x 16 slabs of 512 rows), block = 512 (8 waves).
// wave w owns rows [slab*512 + w*64, +64) = 2 chunks of 32 rows, fully
// independent after the one staging barrier.
__global__ __launch_bounds__(512) void attn_main(
    const float* __restrict__ enc, const _Float16* __restrict__ Bfrag,
    const float* __restrict__ qb, const float* __restrict__ v,
    float* __restrict__ logits, float* __restrict__ P,
    float* __restrict__ mw, float* __restrict__ lw)
{
  __shared__ _Float16 Wf[65536];   // 128 KiB: We fragments (A-operand), frag order
  __shared__ float2 qv2[256];      // {qb[b][k], v[k]}

  const int tid = threadIdx.x, wv = tid >> 6, lane = tid & 63;
  const int q = lane >> 4, lc = lane & 15;
  const int b = blockIdx.x >> 4, slab = blockIdx.x & 15;
  const int rowBase0 = b * 8192 + slab * 512 + wv * 64;   // wave's 64 rows

  float4 pf[2][8][2];              // raw f32 of one 32-row chunk (128 VGPRs)
  f16x8 bfA[2][8], bfB[2][8];      // f16 fragments, chunk 0 / chunk 1

  // issue raw loads for chunk `base` (32 rows). lane (q,lc), tile t:
  // row = base + lc + 16t, cols q*8..q*8+7 (+32kc); pair covers 32B/lane/kc.
  #define LOAD_RAW(base)                                                    \
  {                                                                         \
    _Pragma("unroll")                                                       \
    for (int t = 0; t < 2; t++){                                            \
      const float* er = enc + (size_t)((base) + lc + 16 * t) * 256 + q * 8; \
      _Pragma("unroll")                                                     \
      for (int kc = 0; kc < 8; kc++){                                       \
        pf[t][kc][0] = *(const float4*)(er + kc * 32);                      \
        pf[t][kc][1] = *(const float4*)(er + kc * 32 + 4);                  \
      }                                                                     \
    }                                                                       \
  }
  #define CVT(bfX)                                                          \
  {                                                                         \
    _Pragma("unroll")                                                       \
    for (int t = 0; t < 2; t++)                                             \
      _Pragma("unroll")                                                     \
      for (int kc = 0; kc < 8; kc++){                                       \
        f16x8 h;                                                            \
        h[0]=(_Float16)pf[t][kc][0].x; h[1]=(_Float16)pf[t][kc][0].y;       \
        h[2]=(_Float16)pf[t][kc][0].z; h[3]=(_Float16)pf[t][kc][0].w;       \
        h[4]=(_Float16)pf[t][kc][1].x; h[5]=(_Float16)pf[t][kc][1].y;       \
        h[6]=(_Float16)pf[t][kc][1].z; h[7]=(_Float16)pf[t][kc][1].w;       \
        bfX[t][kc] = h;                                                     \
      }                                                                     \
  }

  // ---- issue chunk-0 loads FIRST (HBM latency hides under We staging) ----
  LOAD_RAW(rowBase0)

  // ---- stage We frags (128 KiB) + qv2, once per block ----
  {
    const float4* src = (const float4*)Bfrag;
    float4* dst = (float4*)Wf;
    #pragma unroll
    for (int i = 0; i < 16; i++) dst[tid + i * 512] = src[tid + i * 512];
    if (tid < 256) qv2[tid] = make_float2(qb[b * 256 + tid], v[tid]);
  }
  CVT(bfA)
  __syncthreads();                 // the ONLY barrier (nothing outstanding here)

  // ---- issue chunk-1 loads; they stay in flight across all of MFMA0 ----
  LOAD_RAW(rowBase0 + 32)

  const f16x8* Wl = (const f16x8*)Wf;

  // per-chunk compute: scores^T GEMM -> logits -> wave softmax -> L3-hot ctx
  auto compute_chunk = [&](f16x8 (&bf)[2][8], int ci){
    const int rowBase = rowBase0 + ci * 32;
    const int cid = b * 256 + slab * 16 + wv * 2 + ci;

    // D[kout = q*4+rr (+16nt)][row = lc (+16t)]
    float lg0 = 0.f, lg1 = 0.f;
    __builtin_amdgcn_s_setprio(1);
    #pragma unroll 2
    for (int nt = 0; nt < 16; nt++){
      f32x4 acc0 = {0, 0, 0, 0}, acc1 = {0, 0, 0, 0};
      #pragma unroll
      for (int kc = 0; kc < 8; kc++){
        f16x8 a = Wl[(nt * 8 + kc) * 64 + lane];
        acc0 = __builtin_amdgcn_mfma_f32_16x16x32_f16(a, bf[0][kc], acc0, 0, 0, 0);
        acc1 = __builtin_amdgcn_mfma_f32_16x16x32_f16(a, bf[1][kc], acc1, 0, 0, 0);
      }
      #pragma unroll
      for (int rr = 0; rr < 4; rr++){
        float2 c = qv2[nt * 16 + q * 4 + rr];
        lg0 += fast_tanh(acc0[rr] + c.x) * c.y;
        lg1 += fast_tanh(acc1[rr] + c.x) * c.y;
      }
    }
    __builtin_amdgcn_s_setprio(0);

    // chunk 0 only: convert chunk-1 raw (loads have landed under MFMA0)
    if (ci == 0) CVT(bfB)

    // finish logits: sum the 4 kout-groups (q); result replicated over q
    lg0 += __shfl_xor(lg0, 16); lg0 += __shfl_xor(lg0, 32);
    lg1 += __shfl_xor(lg1, 16); lg1 += __shfl_xor(lg1, 32);
    if (q == 0){
      logits[rowBase + lc]      = lg0;
      logits[rowBase + 16 + lc] = lg1;
    }
    // wave-local softmax over 32 rows
    float m = fmaxf(lg0, lg1);
    m = fmaxf(m, __shfl_xor(m, 1)); m = fmaxf(m, __shfl_xor(m, 2));
    m = fmaxf(m, __shfl_xor(m, 4)); m = fmaxf(m, __shfl_xor(m, 8));
    float e0 = __expf(lg0 - m), e1 = __expf(lg1 - m);
    float ls = e0 + e1;
    ls += __shfl_xor(ls, 1); ls += __shfl_xor(ls, 2);
    ls += __shfl_xor(ls, 4); ls += __shfl_xor(ls, 8);
    if (lane == 0){ mw[cid] = m; lw[cid] = ls; }

    // context: f32 enc re-read (L3-hot, rows just streamed), lane owns 4 cols
    float4 ctx = make_float4(0.f, 0.f, 0.f, 0.f);
    const float* ep = enc + (size_t)rowBase * 256 + lane * 4;
    #pragma unroll
    for (int r = 0; r < 16; r++){
      float w0 = lane_bcast(e0, r);          // weight of row r
      float w1 = lane_bcast(e1, r);          // weight of row 16+r
      float4 a  = *(const float4*)(ep + (size_t)r * 256);
      float4 b4 = *(const float4*)(ep + (size_t)(r + 16) * 256);
      ctx.x += w0 * a.x + w1 * b4.x;
      ctx.y += w0 * a.y + w1 * b4.y;
      ctx.z += w0 * a.z + w1 * b4.z;
      ctx.w += w0 * a.w + w1 * b4.w;
    }
    *(float4*)(P + (size_t)cid * 256 + lane * 4) = ctx;
  };

  compute_chunk(bfA, 0);
  compute_chunk(bfB, 1);
  #undef LOAD_RAW
  #undef CVT
}

// ---------------- finish (unchanged, verified) ----------------
// grid = 64 (2 per batch: half 0 also does context; weights split), block = 256
__global__ void attn_finish(const float* __restrict__ logits, const float* __restrict__ P,
                            const float* __restrict__ mw, const float* __restrict__ lw,
                            float* __restrict__ out)
{
  const int b = blockIdx.x >> 1, half = blockIdx.x & 1, t = threadIdx.x;
  __shared__ float se[256], red[8];
  float mv = mw[b * 256 + t], lv = lw[b * 256 + t];
  float m = mv;
  #pragma unroll
  for (int o = 1; o < 64; o <<= 1) m = fmaxf(m, __shfl_xor(m, o));
  if ((t & 63) == 0) red[t >> 6] = m;
  __syncthreads();
  const float M = fmaxf(fmaxf(red[0], red[1]), fmaxf(red[2], red[3]));
  float e = __expf(mv - M);
  se[t] = e;
  float l = e * lv;
  #pragma unroll
  for (int o = 1; o < 64; o <<= 1) l += __shfl_xor(l, o);
  if ((t & 63) == 0) red[4 + (t >> 6)] = l;
  __syncthreads();
  const float L = red[4] + red[5] + red[6] + red[7];
  const float inv = 1.f / L;
  if (half == 0){
    float c0 = 0.f, c1 = 0.f;
    #pragma unroll 8
    for (int ch = 0; ch < 128; ch++){
      c0 += se[ch]       * P[(size_t)(b * 256 + ch) * 256 + t];
      c1 += se[ch + 128] * P[(size_t)(b * 256 + 128 + ch) * 256 + t];
    }
    out[b * 256 + t] = (c0 + c1) * inv;
  }
  const float* lg = logits + (size_t)b * 8192 + half * 4096;
  float* ao = out + 8192 + (size_t)b * 8192 + half * 4096;
  #pragma unroll
  for (int s2 = 0; s2 < 16; s2++) ao[s2 * 256 + t] = __expf(lg[s2 * 256 + t] - M) * inv;
}

extern "C" void kernel_launch(void* const* d_in, const int* in_sizes, int n_in,
                              void* d_out, int out_size, void* d_ws, size_t ws_size,
                              hipStream_t stream)
{
  const float* hidden = (const float*)d_in[0];   // (1,32,256)
  const float* enc    = (const float*)d_in[1];   // (32,8192,256)
  const float* W      = (const float*)d_in[2];   // (256,512)
  const float* bias   = (const float*)d_in[3];   // (256,)
  const float* v      = (const float*)d_in[4];   // (256,)
  float* out = (float*)d_out;

  char* ws = (char*)d_ws;
  _Float16* Bfrag = (_Float16*)ws;                                       // 128 KiB
  float* qb     = (float*)(ws + (128 << 10));                            // 32 KiB
  float* logits = (float*)(ws + (160 << 10));                            // 1 MiB
  float* P      = (float*)(ws + (160 << 10) + (1 << 20));                // 8 MiB (8192*256*4)
  float* mw     = (float*)(ws + (160 << 10) + (9 << 20));                // 32 KiB
  float* lw     = (float*)(ws + (160 << 10) + (9 << 20) + (32 << 10));   // 32 KiB

  prep_kernel<<<288, 256, 0, stream>>>(hidden, W, bias, Bfrag, qb);
  attn_main<<<512, 512, 0, stream>>>(enc, Bfrag, qb, v, logits, P, mw, lw);
  attn_finish<<<64, 256, 0, stream>>>(logits, P, mw, lw, out);
}